// Round 4
// baseline (106.606 us; speedup 1.0000x reference)
//
#include <hip/hip_runtime.h>
#include <math.h>

#pragma clang fp contract(off)

// Problem constants (fixed shapes from the reference)
#define CCH   192          // B*c = 64*3
#define HW    (512*512)    // 262144 pixels per channel
#define RNUM  8            // region_num
#define SPLIT 8            // reduction blocks per channel in pass 1

// ws layout (floats):
//   [0, CCH*SPLIT*2)              partial min/max pairs
//   [PARAM_OFF, PARAM_OFF+CCH*16) per-channel params: 7 boundaries + 8 rand_vals
#define PART_FLOATS (CCH * SPLIT * 2)
#define PARAM_OFF   PART_FLOATS

// ---------------------------------------------------------------------------
// Un-contractible fp32 RN ops. HIP's __fmul_rn/__fadd_rn are plain a*b / a+b
// and hipcc defaults to -ffp-contract=fast-honor-pragmas, which fused my
// mul+add into FMA in round 1 (the correctness bug). Inline asm is guaranteed
// single-rounding, never contracted.
// ---------------------------------------------------------------------------
__device__ __forceinline__ float mul_rn(float a, float b) {
    float r; asm volatile("v_mul_f32 %0, %1, %2" : "=v"(r) : "v"(a), "v"(b)); return r;
}
__device__ __forceinline__ float add_rn(float a, float b) {
    float r; asm volatile("v_add_f32 %0, %1, %2" : "=v"(r) : "v"(a), "v"(b)); return r;
}
__device__ __forceinline__ float sub_rn(float a, float b) {
    float r; asm volatile("v_sub_f32 %0, %1, %2" : "=v"(r) : "v"(a), "v"(b)); return r;
}

// ---------------------------------------------------------------------------
// Pass 1: per-(channel, split) min/max partial reduction. float4 loads,
// LDS tree reduce (min/max are exact, order-independent).
// ---------------------------------------------------------------------------
__global__ __launch_bounds__(256) void k_minmax(const float* __restrict__ x,
                                                float* __restrict__ ws) {
    __shared__ float smn[256], smx[256];
    const int chan = blockIdx.x / SPLIT;
    const int part = blockIdx.x % SPLIT;
    const int n4   = HW / 4 / SPLIT;  // 8192 float4 per block

    const float4* px = (const float4*)(x + (size_t)chan * HW) + (size_t)part * n4;

    float mn = INFINITY, mx = -INFINITY;
    for (int i = threadIdx.x; i < n4; i += 256) {
        float4 v = px[i];
        mn = fminf(mn, fminf(fminf(v.x, v.y), fminf(v.z, v.w)));
        mx = fmaxf(mx, fmaxf(fmaxf(v.x, v.y), fmaxf(v.z, v.w)));
    }
    smn[threadIdx.x] = mn;
    smx[threadIdx.x] = mx;
    __syncthreads();
    for (int s = 128; s > 0; s >>= 1) {
        if (threadIdx.x < s) {
            smn[threadIdx.x] = fminf(smn[threadIdx.x], smn[threadIdx.x + s]);
            smx[threadIdx.x] = fmaxf(smx[threadIdx.x], smx[threadIdx.x + s]);
        }
        __syncthreads();
    }
    if (threadIdx.x == 0) {
        ws[(size_t)blockIdx.x * 2 + 0] = smn[0];
        ws[(size_t)blockIdx.x * 2 + 1] = smx[0];
    }
}

// ---------------------------------------------------------------------------
// Pass 2: one thread per channel — finish min/max, build sorted boundaries
// and rand_vals. All arithmetic single-rounded fp32 (inline asm), matching an
// unfused float32 numpy evaluation bit-for-bit:
//   pos       = rn(rn(rp * rn(max-min)) + min)
//   rand_val  = rn(left + rn(proxy * rn(right-left))),  right_last = rn(max+1e-6)
// ---------------------------------------------------------------------------
__global__ void k_params(const float* __restrict__ ws_part,
                         const float* __restrict__ region_percentiles,
                         const float* __restrict__ proxy_percentiles,
                         float* __restrict__ params) {
    const int ch = blockIdx.x * blockDim.x + threadIdx.x;
    if (ch >= CCH) return;

    float mn = INFINITY, mx = -INFINITY;
    #pragma unroll
    for (int p = 0; p < SPLIT; ++p) {
        mn = fminf(mn, ws_part[(ch * SPLIT + p) * 2 + 0]);
        mx = fmaxf(mx, ws_part[(ch * SPLIT + p) * 2 + 1]);
    }
    const float range = sub_rn(mx, mn);

    float pos[RNUM - 1];
    #pragma unroll
    for (int i = 0; i < RNUM - 1; ++i) {
        pos[i] = add_rn(mul_rn(region_percentiles[ch * (RNUM - 1) + i], range), mn);
    }
    // insertion sort (7 elements)
    for (int i = 1; i < RNUM - 1; ++i) {
        float v = pos[i];
        int j = i - 1;
        while (j >= 0 && pos[j] > v) { pos[j + 1] = pos[j]; --j; }
        pos[j + 1] = v;
    }

    float* P = params + (size_t)ch * 16;
    #pragma unroll
    for (int i = 0; i < RNUM - 1; ++i) P[i] = pos[i];
    #pragma unroll
    for (int i = 0; i < RNUM; ++i) {
        const float left  = (i == 0)        ? mn : pos[i - 1];
        const float right = (i == RNUM - 1) ? add_rn(mx, 1e-6f) : pos[i];
        P[RNUM - 1 + i] = add_rn(left,
                                 mul_rn(proxy_percentiles[ch * RNUM + i],
                                        sub_rn(right, left)));
    }
}

// ---------------------------------------------------------------------------
// Pass 3: per-pixel region id + gather, pure fp32.
// id = count(boundary <= v)  (== searchsorted side='right').
// ---------------------------------------------------------------------------
#define BLOCKS_PER_CH 16
__global__ __launch_bounds__(256) void k_apply(const float* __restrict__ x,
                                               const float* __restrict__ params,
                                               float* __restrict__ out) {
    const int chan = blockIdx.x / BLOCKS_PER_CH;
    const int blk  = blockIdx.x % BLOCKS_PER_CH;
    const int n4   = HW / 4 / BLOCKS_PER_CH;  // 4096 float4 per block

    __shared__ float sb[RNUM - 1];
    __shared__ float srv[RNUM];
    if (threadIdx.x < 2 * RNUM - 1) {
        const float v = params[(size_t)chan * 16 + threadIdx.x];
        if (threadIdx.x < RNUM - 1) sb[threadIdx.x] = v;
        else                        srv[threadIdx.x - (RNUM - 1)] = v;
    }
    __syncthreads();

    const float b0 = sb[0], b1 = sb[1], b2 = sb[2], b3 = sb[3];
    const float b4 = sb[4], b5 = sb[5], b6 = sb[6];

    const float4* px = (const float4*)(x   + (size_t)chan * HW) + (size_t)blk * n4;
    float4*       po = (float4*)      (out + (size_t)chan * HW) + (size_t)blk * n4;

    for (int i = threadIdx.x; i < n4; i += 256) {
        const float4 v = px[i];
        float4 o;
        {
            int id = (b0 <= v.x) + (b1 <= v.x) + (b2 <= v.x) + (b3 <= v.x)
                   + (b4 <= v.x) + (b5 <= v.x) + (b6 <= v.x);
            o.x = srv[id];
        }
        {
            int id = (b0 <= v.y) + (b1 <= v.y) + (b2 <= v.y) + (b3 <= v.y)
                   + (b4 <= v.y) + (b5 <= v.y) + (b6 <= v.y);
            o.y = srv[id];
        }
        {
            int id = (b0 <= v.z) + (b1 <= v.z) + (b2 <= v.z) + (b3 <= v.z)
                   + (b4 <= v.z) + (b5 <= v.z) + (b6 <= v.z);
            o.z = srv[id];
        }
        {
            int id = (b0 <= v.w) + (b1 <= v.w) + (b2 <= v.w) + (b3 <= v.w)
                   + (b4 <= v.w) + (b5 <= v.w) + (b6 <= v.w);
            o.w = srv[id];
        }
        po[i] = o;
    }
}

// ---------------------------------------------------------------------------
extern "C" void kernel_launch(void* const* d_in, const int* in_sizes, int n_in,
                              void* d_out, int out_size, void* d_ws, size_t ws_size,
                              hipStream_t stream) {
    const float* x  = (const float*)d_in[0];
    const float* rp = (const float*)d_in[1];  // region_percentiles, C*(R-1)
    const float* pp = (const float*)d_in[2];  // proxy_percentiles,  C*R
    // d_in[3] = region_num (hard-coded 8, matches reference constant)
    float* out = (float*)d_out;
    float* ws  = (float*)d_ws;

    k_minmax<<<CCH * SPLIT, 256, 0, stream>>>(x, ws);
    k_params<<<1, 256, 0, stream>>>(ws, rp, pp, ws + PARAM_OFF);
    k_apply<<<CCH * BLOCKS_PER_CH, 256, 0, stream>>>(x, ws + PARAM_OFF, out);
}

// Round 5
// 96.876 us; speedup vs baseline: 1.1004x; 1.1004x over previous
//
#include <hip/hip_runtime.h>
#include <math.h>

#pragma clang fp contract(off)

// Problem constants (fixed shapes from the reference)
#define CCH   192          // B*c = 64*3
#define HW    (512*512)    // 262144 pixels per channel
#define RNUM  8            // region_num
#define SPLIT 8            // reduction blocks per channel in pass 1

typedef float f32x4 __attribute__((ext_vector_type(4)));

// ---------------------------------------------------------------------------
// Un-contractible fp32 RN ops. HIP's __fmul_rn/__fadd_rn are plain a*b / a+b
// and hipcc defaults to -ffp-contract=fast-honor-pragmas, which fused mul+add
// into FMA in round 1 (boundary off by 1 ulp -> region flips). Inline asm is
// guaranteed single-rounding, never contracted. absmax==0.0 confirmed r4.
// ---------------------------------------------------------------------------
__device__ __forceinline__ float mul_rn(float a, float b) {
    float r; asm volatile("v_mul_f32 %0, %1, %2" : "=v"(r) : "v"(a), "v"(b)); return r;
}
__device__ __forceinline__ float add_rn(float a, float b) {
    float r; asm volatile("v_add_f32 %0, %1, %2" : "=v"(r) : "v"(a), "v"(b)); return r;
}
__device__ __forceinline__ float sub_rn(float a, float b) {
    float r; asm volatile("v_sub_f32 %0, %1, %2" : "=v"(r) : "v"(a), "v"(b)); return r;
}

// ---------------------------------------------------------------------------
// Pass 1: per-(channel, split) min/max partial reduction. float4 loads,
// LDS tree reduce (min/max exact, order-independent). Normal (caching) loads
// on purpose: this pass makes x resident in the 256 MiB L3 for pass 2.
// ---------------------------------------------------------------------------
__global__ __launch_bounds__(256) void k_minmax(const float* __restrict__ x,
                                                float* __restrict__ ws) {
    __shared__ float smn[256], smx[256];
    const int chan = blockIdx.x / SPLIT;
    const int part = blockIdx.x % SPLIT;
    const int n4   = HW / 4 / SPLIT;  // 8192 float4 per block

    const f32x4* px = (const f32x4*)(x + (size_t)chan * HW) + (size_t)part * n4;

    float mn = INFINITY, mx = -INFINITY;
    for (int i = threadIdx.x; i < n4; i += 256) {
        f32x4 v = px[i];
        mn = fminf(mn, fminf(fminf(v.x, v.y), fminf(v.z, v.w)));
        mx = fmaxf(mx, fmaxf(fmaxf(v.x, v.y), fmaxf(v.z, v.w)));
    }
    smn[threadIdx.x] = mn;
    smx[threadIdx.x] = mx;
    __syncthreads();
    for (int s = 128; s > 0; s >>= 1) {
        if (threadIdx.x < s) {
            smn[threadIdx.x] = fminf(smn[threadIdx.x], smn[threadIdx.x + s]);
            smx[threadIdx.x] = fmaxf(smx[threadIdx.x], smx[threadIdx.x + s]);
        }
        __syncthreads();
    }
    if (threadIdx.x == 0) {
        ws[(size_t)blockIdx.x * 2 + 0] = smn[0];
        ws[(size_t)blockIdx.x * 2 + 1] = smx[0];
    }
}

// ---------------------------------------------------------------------------
// Pass 2 (fused): each block redundantly computes its channel's params from
// the 16 partial floats (bit-identical across blocks, ~60 scalar RN ops on
// thread 0 — hidden), then does per-pixel region id + gather.
//   pos      = rn(rn(rp * rn(max-min)) + min), sorted
//   rand_val = rn(left + rn(proxy * rn(right-left))), right_last = rn(max+1e-6)
//   id       = count(pos <= v)   (== searchsorted side='right')
// Output uses NON-TEMPORAL stores so the 192 MiB write stream does not evict
// x from L3 -> the x re-read stays L3-resident.
// ---------------------------------------------------------------------------
#define BLOCKS_PER_CH 16
__global__ __launch_bounds__(256) void k_apply(const float* __restrict__ x,
                                               const float* __restrict__ ws_part,
                                               const float* __restrict__ region_percentiles,
                                               const float* __restrict__ proxy_percentiles,
                                               float* __restrict__ out) {
    const int chan = blockIdx.x / BLOCKS_PER_CH;
    const int blk  = blockIdx.x % BLOCKS_PER_CH;
    const int n4   = HW / 4 / BLOCKS_PER_CH;  // 4096 float4 per block

    __shared__ float spart[2 * SPLIT];
    __shared__ float sb[RNUM - 1];
    __shared__ float srv[RNUM];

    if (threadIdx.x < 2 * SPLIT)
        spart[threadIdx.x] = ws_part[chan * 2 * SPLIT + threadIdx.x];
    __syncthreads();

    if (threadIdx.x == 0) {
        float mn = INFINITY, mx = -INFINITY;
        #pragma unroll
        for (int p = 0; p < SPLIT; ++p) {
            mn = fminf(mn, spart[2 * p + 0]);
            mx = fmaxf(mx, spart[2 * p + 1]);
        }
        const float range = sub_rn(mx, mn);

        float pos[RNUM - 1];
        #pragma unroll
        for (int i = 0; i < RNUM - 1; ++i)
            pos[i] = add_rn(mul_rn(region_percentiles[chan * (RNUM - 1) + i], range), mn);
        // insertion sort (7 elements)
        for (int i = 1; i < RNUM - 1; ++i) {
            float v = pos[i];
            int j = i - 1;
            while (j >= 0 && pos[j] > v) { pos[j + 1] = pos[j]; --j; }
            pos[j + 1] = v;
        }
        #pragma unroll
        for (int i = 0; i < RNUM - 1; ++i) sb[i] = pos[i];
        #pragma unroll
        for (int i = 0; i < RNUM; ++i) {
            const float left  = (i == 0)        ? mn : pos[i - 1];
            const float right = (i == RNUM - 1) ? add_rn(mx, 1e-6f) : pos[i];
            srv[i] = add_rn(left,
                            mul_rn(proxy_percentiles[chan * RNUM + i],
                                   sub_rn(right, left)));
        }
    }
    __syncthreads();

    const float b0 = sb[0], b1 = sb[1], b2 = sb[2], b3 = sb[3];
    const float b4 = sb[4], b5 = sb[5], b6 = sb[6];

    const f32x4* px = (const f32x4*)(x   + (size_t)chan * HW) + (size_t)blk * n4;
    f32x4*       po = (f32x4*)      (out + (size_t)chan * HW) + (size_t)blk * n4;

    for (int i = threadIdx.x; i < n4; i += 256) {
        const f32x4 v = px[i];
        f32x4 o;
        {
            int id = (b0 <= v.x) + (b1 <= v.x) + (b2 <= v.x) + (b3 <= v.x)
                   + (b4 <= v.x) + (b5 <= v.x) + (b6 <= v.x);
            o.x = srv[id];
        }
        {
            int id = (b0 <= v.y) + (b1 <= v.y) + (b2 <= v.y) + (b3 <= v.y)
                   + (b4 <= v.y) + (b5 <= v.y) + (b6 <= v.y);
            o.y = srv[id];
        }
        {
            int id = (b0 <= v.z) + (b1 <= v.z) + (b2 <= v.z) + (b3 <= v.z)
                   + (b4 <= v.z) + (b5 <= v.z) + (b6 <= v.z);
            o.z = srv[id];
        }
        {
            int id = (b0 <= v.w) + (b1 <= v.w) + (b2 <= v.w) + (b3 <= v.w)
                   + (b4 <= v.w) + (b5 <= v.w) + (b6 <= v.w);
            o.w = srv[id];
        }
        __builtin_nontemporal_store(o, &po[i]);
    }
}

// ---------------------------------------------------------------------------
extern "C" void kernel_launch(void* const* d_in, const int* in_sizes, int n_in,
                              void* d_out, int out_size, void* d_ws, size_t ws_size,
                              hipStream_t stream) {
    const float* x  = (const float*)d_in[0];
    const float* rp = (const float*)d_in[1];  // region_percentiles, C*(R-1)
    const float* pp = (const float*)d_in[2];  // proxy_percentiles,  C*R
    // d_in[3] = region_num (hard-coded 8, matches reference constant)
    float* out = (float*)d_out;
    float* ws  = (float*)d_ws;

    k_minmax<<<CCH * SPLIT, 256, 0, stream>>>(x, ws);
    k_apply<<<CCH * BLOCKS_PER_CH, 256, 0, stream>>>(x, ws, rp, pp, out);
}